// Round 11
// baseline (153.820 us; speedup 1.0000x reference)
//
#include <hip/hip_runtime.h>

#define NB 8
#define NL 2048
#define ND 128
#define NH 128
#define MASKVAL (-1e30f)
#define SHIFTC 40.0f

typedef __attribute__((ext_vector_type(8))) short short8;
typedef __attribute__((ext_vector_type(4))) float f32x4;

__device__ __forceinline__ unsigned short bf16_rn(float f) {
  unsigned u = __float_as_uint(f);
  u += 0x7fffu + ((u >> 16) & 1u);
  return (unsigned short)(u >> 16);
}
__device__ __forceinline__ float bf16_tof(unsigned short h) {
  return __uint_as_float(((unsigned)h) << 16);
}
// global->LDS DMA: per-lane global src, wave-uniform LDS base (+lane*16 by HW)
__device__ __forceinline__ void gload16(const void* g, void* l) {
  __builtin_amdgcn_global_load_lds(
      (const __attribute__((address_space(1))) unsigned*)g,
      (__attribute__((address_space(3))) unsigned*)l, 16, 0, 0);
}

// kvs tile layout (per (b, kt) of 32 keys): 12288 shorts = 24 KB
//   [0:4096)     K-hi  short off = row*128 + ((ch ^ (row&7))*8 + (col&7))
//   [4096:8192)  K-lo  same
//   [8192:12288) V^T   granule cp = (d*4+g)^(d&7); slot j of granule g holds
//                      key g*4 + (j&3) + 16*(j>>2)   (PV-permuted order)

// ---------- Kernel 0: W transpose + hi/lo split (LDS-bounce, coalesced) ---
__global__ __launch_bounds__(256) void wprep_kernel(
    const float* __restrict__ Wq, const float* __restrict__ Wk,
    short* __restrict__ wthq, short* __restrict__ wtlq,
    short* __restrict__ wthk, short* __restrict__ wtlk)
{
  __shared__ short Th[128][34];
  __shared__ short Tll[128][34];
  int m = blockIdx.x >> 2, dt = blockIdx.x & 3;   // matrix, 32-row d-tile
  const float* W = m ? Wk : Wq;
  short* th = m ? wthk : wthq;
  short* tl = m ? wtlk : wtlq;
  int tid = threadIdx.x;
#pragma unroll
  for (int c = 0; c < 16; ++c) {
    int idx = c * 256 + tid;          // 0..4095
    int dl = idx >> 7, h = idx & 127;
    float v = W[(dt * 32 + dl) * NH + h];
    unsigned short hb = bf16_rn(v);
    Th[h][dl] = (short)hb;
    Tll[h][dl] = (short)bf16_rn(v - bf16_tof(hb));
  }
  __syncthreads();
#pragma unroll
  for (int c = 0; c < 16; ++c) {
    int idx = c * 256 + tid;          // 0..4095 u32s (2 planes x 128 h x 16)
    int plane = idx >> 11, rest = idx & 2047;
    int h = rest >> 4, du = rest & 15;
    unsigned v = plane ? *(const unsigned*)&Tll[h][du * 2]
                       : *(const unsigned*)&Th[h][du * 2];
    short* dst = plane ? tl : th;
    *(unsigned*)&dst[h * ND + dt * 32 + du * 2] = v;
  }
}

// ---------- Kernel 1: V transpose -> kvs VT section (permuted, LDS bounce)
__global__ __launch_bounds__(256) void vtprep_kernel(
    const float* __restrict__ value, short* __restrict__ kvs)
{
  __shared__ short Tl[64][66];
  __shared__ short VB[2][2048];       // 2 tiles x 256 granules x 8 shorts
  int b = blockIdx.x >> 6;
  int k0 = ((blockIdx.x >> 1) & 31) * 64;
  int d0 = (blockIdx.x & 1) * 64;
  int t = threadIdx.x;
  int dm = t & 7, kp = t >> 3;
  float v0[8], v1[8];
  {
    const float* vp0 = value + (size_t)(b * NL + k0 + kp * 2) * ND + d0 + dm * 8;
    const float* vp1 = vp0 + ND;
    float4 a0 = *(const float4*)vp0;       float4 c0 = *(const float4*)(vp0 + 4);
    float4 a1 = *(const float4*)vp1;       float4 c1 = *(const float4*)(vp1 + 4);
    v0[0]=a0.x; v0[1]=a0.y; v0[2]=a0.z; v0[3]=a0.w; v0[4]=c0.x; v0[5]=c0.y; v0[6]=c0.z; v0[7]=c0.w;
    v1[0]=a1.x; v1[1]=a1.y; v1[2]=a1.z; v1[3]=a1.w; v1[4]=c1.x; v1[5]=c1.y; v1[6]=c1.z; v1[7]=c1.w;
  }
#pragma unroll
  for (int j = 0; j < 8; ++j) {
    unsigned pk = (unsigned)bf16_rn(v0[j]) | ((unsigned)bf16_rn(v1[j]) << 16);
    *(unsigned*)&Tl[dm * 8 + j][kp * 2] = pk;
  }
  __syncthreads();
  int dr = t >> 2, kc4 = t & 3;
  const unsigned* base = (const unsigned*)&Tl[dr][0];
  unsigned w[8];
#pragma unroll
  for (int i = 0; i < 8; ++i) w[i] = base[kc4 * 8 + i];   // keys 2i,2i+1 of half
  int jt = kc4 >> 1, hh = kc4 & 1;
#pragma unroll
  for (int i = 0; i < 8; ++i) {
    int g = i >> 1;
    int lg = (dr * 4 + g) ^ (dr & 7);
    int jslot = ((2 * i) & 3) + 4 * hh;
    *(unsigned*)&VB[jt][lg * 8 + jslot] = w[i];
  }
  __syncthreads();
  int kt = k0 >> 5;
#pragma unroll
  for (int c = 0; c < 2; ++c) {
    int idx = c * 256 + t;            // 0..511
    int j = idx >> 8, off = (idx & 255) * 8;
    *(uint4*)(kvs + (size_t)(b * 64 + kt + j) * 12288 + 8192 + d0 * 32 + off) =
        *(const uint4*)&VB[j][off];
  }
}

// ---------- Kernel 2: projection (split-bf16 MFMA) ------------------------
__global__ __launch_bounds__(256) void proj_kernel(
    const float* __restrict__ query, const float* __restrict__ key,
    const short* __restrict__ wthq, const short* __restrict__ wtlq,
    const short* __restrict__ wthk, const short* __restrict__ wtlk,
    unsigned* __restrict__ qhl, short* __restrict__ kvs)
{
  __shared__ short KB2[16384];        // 2 tiles x (Khi 4096 | Klo 4096)
  const float* X = blockIdx.y ? key : query;
  const short* wth = blockIdx.y ? wthk : wthq;
  const short* wtl = blockIdx.y ? wtlk : wtlq;

  int tid = threadIdx.x;
  int wave = tid >> 6, lane = tid & 63;
  int lr = lane & 15, dg = lane >> 4;
  int arow = blockIdx.x * 64 + wave * 16 + lr;

  short8 ah[4], al[4];
  const float* xr = X + (size_t)arow * ND;
#pragma unroll
  for (int ks = 0; ks < 4; ++ks) {
    float4 a0 = *(const float4*)(xr + ks * 32 + dg * 8);
    float4 a1 = *(const float4*)(xr + ks * 32 + dg * 8 + 4);
    float vv[8] = {a0.x, a0.y, a0.z, a0.w, a1.x, a1.y, a1.z, a1.w};
    short8 h, l;
#pragma unroll
    for (int j = 0; j < 8; ++j) {
      unsigned short hb = bf16_rn(vv[j]);
      h[j] = (short)hb;
      l[j] = (short)bf16_rn(vv[j] - bf16_tof(hb));
    }
    ah[ks] = h; al[ks] = l;
  }

#pragma unroll
  for (int cf = 0; cf < 8; ++cf) {
    f32x4 acc = {0.f, 0.f, 0.f, 0.f};
    int col = cf * 16 + lr;
    const short* whp = wth + (size_t)col * ND;
    const short* wlp = wtl + (size_t)col * ND;
#pragma unroll
    for (int ks = 0; ks < 4; ++ks) {
      short8 wh = *(const short8*)(whp + ks * 32 + dg * 8);
      short8 wl = *(const short8*)(wlp + ks * 32 + dg * 8);
      acc = __builtin_amdgcn_mfma_f32_16x16x32_bf16(ah[ks], wh, acc, 0, 0, 0);
      acc = __builtin_amdgcn_mfma_f32_16x16x32_bf16(al[ks], wh, acc, 0, 0, 0);
      acc = __builtin_amdgcn_mfma_f32_16x16x32_bf16(ah[ks], wl, acc, 0, 0, 0);
    }
#pragma unroll
    for (int r = 0; r < 4; ++r) {
      int orow = blockIdx.x * 64 + wave * 16 + dg * 4 + r;
      float v = acc[r];
      unsigned short hb = bf16_rn(v);
      unsigned short lb = bf16_rn(v - bf16_tof(hb));
      if (blockIdx.y == 0) {
        qhl[(size_t)orow * NH + col] = ((unsigned)lb << 16) | (unsigned)hb;
      } else {
        int jj = (orow >> 5) & 1;
        int krow = orow & 31;
        int gr = krow * 128 + (((col >> 3) ^ (krow & 7)) * 8) + (col & 7);
        KB2[jj * 8192 + gr] = (short)hb;
        KB2[jj * 8192 + 4096 + gr] = (short)lb;
      }
    }
  }
  if (blockIdx.y == 1) {
    __syncthreads();
    int r0 = blockIdx.x * 64;
    int bb2 = r0 >> 11;
    int kt0 = (r0 & (NL - 1)) >> 5;
#pragma unroll
    for (int c = 0; c < 8; ++c) {
      int idx = c * 256 + tid;        // 0..2047
      int j = idx >> 10, off = (idx & 1023) * 8;
      *(uint4*)(kvs + (size_t)(bb2 * 64 + kt0 + j) * 12288 + off) =
          *(const uint4*)&KB2[j * 8192 + off];
    }
  }
}

// ---------- Kernel 3: attention partial (split-K, swapped QK^T) -----------
// grid 256*nseg: b = bid&7 (XCD), qt = (bid>>3)&31, seg = bid>>8.
// Swapped MFMA: sc = K·Q^T -> lane holds P for q=lr, keys {dg*4+r, 16+dg*4+r}
// = exactly the PV A-frag under the permuted V^T order. No P LDS round-trip.
__global__ __launch_bounds__(256, 3) void attn_kernel(
    const unsigned* __restrict__ qhl, const short* __restrict__ kvs,
    const float* __restrict__ mask,
    unsigned short* __restrict__ pacc, float* __restrict__ pl,
    int nseg, int tiles)
{
  __shared__ short KV[2][12288];      // 48 KB double-buffered tile
  __shared__ float Msk[1024];         // this segment's mask keys (max 4 KB)

  int tid = threadIdx.x;
  int w = tid >> 6, lane = tid & 63;
  int lr = lane & 15, dg = lane >> 4;
  int b = blockIdx.x & 7;
  int qt = (blockIdx.x >> 3) & 31;
  int seg = blockIdx.x >> 8;
  int q0 = qt * 64;

  // Q fragments (packed hi|lo u32 -> split), rows q0 + w*16 + lr
  short8 qh[4], ql[4];
  {
    const unsigned* qp = qhl + (size_t)(b * NL + q0 + w * 16 + lr) * NH;
#pragma unroll
    for (int ks = 0; ks < 4; ++ks) {
      uint4 u0 = *(const uint4*)(qp + ks * 32 + dg * 8);
      uint4 u1 = *(const uint4*)(qp + ks * 32 + dg * 8 + 4);
      unsigned uv[8] = {u0.x, u0.y, u0.z, u0.w, u1.x, u1.y, u1.z, u1.w};
      short8 h, l;
#pragma unroll
      for (int j = 0; j < 8; ++j) {
        h[j] = (short)(uv[j] & 0xffffu);
        l[j] = (short)(uv[j] >> 16);
      }
      qh[ks] = h; ql[ks] = l;
    }
  }

  // mask for this segment (NL/nseg keys); every wave issues exactly 1 gload
  int mwords = (NL / nseg) / 4;       // floats per wave: 256 (nseg2) / 128 (nseg4)
  if (lane * 4 < mwords)
    gload16(mask + b * NL + seg * (NL / nseg) + w * mwords + lane * 4,
            Msk + w * mwords);

  f32x4 accv[8];
#pragma unroll
  for (int f = 0; f < 8; ++f) accv[f] = (f32x4){0.f, 0.f, 0.f, 0.f};
  float lsum = 0.f;

  const short* gbase = kvs + (size_t)(b * 64 + seg * tiles) * 12288 + w * 3072 + lane * 8;

  // prologue: stage tile 0
#pragma unroll
  for (int i = 0; i < 6; ++i)
    gload16(gbase + i * 512, &KV[0][w * 3072 + i * 512]);

  for (int t = 0; t < tiles; ++t) {
    __builtin_amdgcn_s_barrier();            // buf[(t+1)&1] fully consumed
    if (t + 1 < tiles) {
      const short* gt = gbase + (size_t)(t + 1) * 12288;
      short* lt = &KV[(t + 1) & 1][w * 3072];
#pragma unroll
      for (int i = 0; i < 6; ++i)
        gload16(gt + i * 512, lt + i * 512);
      asm volatile("s_waitcnt vmcnt(6)" ::: "memory");   // stage(t) landed
    } else {
      asm volatile("s_waitcnt vmcnt(0)" ::: "memory");
    }
    __builtin_amdgcn_s_barrier();            // all waves' stage(t) visible
    __builtin_amdgcn_sched_barrier(0);

    const short* Kb = &KV[t & 1][0];
    f32x4 sc0 = {0.f, 0.f, 0.f, 0.f}, sc1 = {0.f, 0.f, 0.f, 0.f};
#pragma unroll
    for (int ks = 0; ks < 4; ++ks) {
      int chp = (((ks * 4 + dg) ^ (lr & 7)) * 8);
      short8 b0h = *(const short8*)(Kb + lr * 128 + chp);
      short8 b0l = *(const short8*)(Kb + 4096 + lr * 128 + chp);
      short8 b1h = *(const short8*)(Kb + (16 + lr) * 128 + chp);
      short8 b1l = *(const short8*)(Kb + 4096 + (16 + lr) * 128 + chp);
      // swapped: A = K fragment, B = Q fragment -> sc = S^T
      sc0 = __builtin_amdgcn_mfma_f32_16x16x32_bf16(b0h, qh[ks], sc0, 0, 0, 0);
      sc1 = __builtin_amdgcn_mfma_f32_16x16x32_bf16(b1h, qh[ks], sc1, 0, 0, 0);
      sc0 = __builtin_amdgcn_mfma_f32_16x16x32_bf16(b0l, qh[ks], sc0, 0, 0, 0);
      sc1 = __builtin_amdgcn_mfma_f32_16x16x32_bf16(b1l, qh[ks], sc1, 0, 0, 0);
      sc0 = __builtin_amdgcn_mfma_f32_16x16x32_bf16(b0h, ql[ks], sc0, 0, 0, 0);
      sc1 = __builtin_amdgcn_mfma_f32_16x16x32_bf16(b1h, ql[ks], sc1, 0, 0, 0);
    }
    // lane: q = lr; sc0[r]: key dg*4+r; sc1[r]: key 16+dg*4+r
    float4 mk0 = *(const float4*)&Msk[t * 32 + dg * 4];
    float4 mk1 = *(const float4*)&Msk[t * 32 + 16 + dg * 4];
    float m0a[4] = {mk0.x, mk0.y, mk0.z, mk0.w};
    float m1a[4] = {mk1.x, mk1.y, mk1.z, mk1.w};
    short8 pa;
    float ps = 0.f;
#pragma unroll
    for (int r = 0; r < 4; ++r) {
      float s0 = m0a[r] * sc0[r] + (1.f - m0a[r]) * MASKVAL - SHIFTC;
      float s1 = m1a[r] * sc1[r] + (1.f - m1a[r]) * MASKVAL - SHIFTC;
      float p0 = __expf(s0), p1 = __expf(s1);
      ps += p0 + p1;
      pa[r] = (short)bf16_rn(p0);
      pa[4 + r] = (short)bf16_rn(p1);
    }
    lsum += ps;
    // PV: pa IS the A-frag (q=lr rows via lanes, k-slots match permuted V^T)
#pragma unroll
    for (int f = 0; f < 8; ++f) {
      int row = f * 16 + lr;
      int cp = (((row * 4 + dg) ^ (row & 7)) * 8);
      short8 bv = *(const short8*)(Kb + 8192 + cp);
      accv[f] = __builtin_amdgcn_mfma_f32_16x16x32_bf16(pa, bv, accv[f], 0, 0, 0);
    }
  }

  // ---- epilogue ----------------------------------------------------------
  // lsum is per-lane partial for q=lr; reduce across dg groups (lanes +16)
  lsum += __shfl_xor(lsum, 16);
  lsum += __shfl_xor(lsum, 32);
  size_t segbase = (size_t)seg * (NB * NL);
  if (lane < 16)
    pl[segbase + b * NL + q0 + w * 16 + lr] = lsum;
  // accv[f][r]: q = dg*4+r, d = f*16+lr (C layout) -> bf16 partial
#pragma unroll
  for (int r = 0; r < 4; ++r) {
    size_t grow = segbase + b * NL + q0 + w * 16 + dg * 4 + r;
    unsigned short* pb = pacc + grow * ND;
#pragma unroll
    for (int f = 0; f < 8; ++f)
      pb[f * 16 + lr] = bf16_rn(accv[f][r]);
  }
}

// ---------- Kernel 4: merge the K-segments --------------------------------
__global__ __launch_bounds__(256) void merge_kernel(
    const unsigned short* __restrict__ pacc, const float* __restrict__ pl,
    float* __restrict__ out, int nseg)
{
  int g = blockIdx.x * 256 + threadIdx.x;   // 0 .. 262143
  int row = g >> 4, ch = g & 15;
  float ls = 0.f;
  for (int s = 0; s < nseg; ++s) ls += pl[(size_t)s * (NB * NL) + row];
  float rinv = 1.f / ls;
  float acc[8] = {0.f, 0.f, 0.f, 0.f, 0.f, 0.f, 0.f, 0.f};
  for (int s = 0; s < nseg; ++s) {
    const unsigned short* a = pacc + ((size_t)s * (NB * NL) + row) * ND + ch * 8;
#pragma unroll
    for (int j = 0; j < 8; ++j) acc[j] += bf16_tof(a[j]);
  }
  float* op = out + (size_t)row * ND + ch * 8;
#pragma unroll
  for (int j = 0; j < 8; ++j) op[j] = acc[j] * rinv;
}

extern "C" void kernel_launch(void* const* d_in, const int* in_sizes, int n_in,
                              void* d_out, int out_size, void* d_ws, size_t ws_size,
                              hipStream_t stream) {
  (void)in_sizes; (void)n_in; (void)out_size;
  const float* query = (const float*)d_in[0];
  const float* key   = (const float*)d_in[1];
  const float* value = (const float*)d_in[2];
  const float* mask  = (const float*)d_in[3];
  const float* Wq    = (const float*)d_in[4];
  const float* Wk    = (const float*)d_in[5];
  float* out = (float*)d_out;

  int nseg = (ws_size >= ((size_t)40 << 20)) ? 4 : 2;
  int tiles = NL / nseg / 32;

  char* ws = (char*)d_ws;
  short* wthq = (short*)(ws);                       // 4 x 32 KB
  short* wtlq = (short*)(ws + (32 << 10));
  short* wthk = (short*)(ws + (64 << 10));
  short* wtlk = (short*)(ws + (96 << 10));
  size_t off = 128 << 10;
  unsigned* qhl = (unsigned*)(ws + off);            // 8 MB
  off += (size_t)8 << 20;
  short* kvs = (short*)(ws + off);                  // 12.6 MB tiled K/V
  off += (size_t)NB * 64 * 12288 * 2;
  unsigned short* pacc = (unsigned short*)(ws + off);  // nseg x 4.2 MB bf16
  off += (size_t)nseg * NB * NL * ND * 2;
  float* pl = (float*)(ws + off);                   // nseg x 64 KB

  wprep_kernel<<<dim3(8), dim3(256), 0, stream>>>(Wq, Wk, wthq, wtlq, wthk, wtlk);
  vtprep_kernel<<<dim3(512), dim3(256), 0, stream>>>(value, kvs);
  proj_kernel<<<dim3(NB * NL / 64, 2), dim3(256), 0, stream>>>(
      query, key, wthq, wtlq, wthk, wtlk, qhl, kvs);
  attn_kernel<<<dim3(256 * nseg), dim3(256), 0, stream>>>(
      qhl, kvs, mask, pacc, pl, nseg, tiles);
  merge_kernel<<<dim3(NB * NL * ND / (256 * 8)), dim3(256), 0, stream>>>(
      pacc, pl, out, nseg);
}